// Round 1
// baseline (1251.903 us; speedup 1.0000x reference)
//
#include <hip/hip_runtime.h>
#include <math.h>

// Problem constants (fixed by the reference: B=256, N=1024, S=16, 21 iters)
static constexpr int S_ = 16;
static constexpr int N_ = 1024;
static constexpr int B_ = 256;
static constexpr int ITERS = 21;
#define EPSC 1e-10f

// la0 = log_alpha + gumbel_noise(u), noise = -log(EPS - log(u + EPS)).
// Fast HW transcendentals: abs error ~1e-5 on la0, vastly below the 7.4e-2
// output threshold (errors enter exp() and are renormalized by Sinkhorn).
__device__ __forceinline__ float la0_of(float uv, float lav) {
    float t1 = __logf(uv + EPSC);
    float t2 = EPSC - t1;
    return lav - __logf(t2);
}

// ---------------------------------------------------------------------------
// Column pass: c[s][j] = c_old + log( sum_i exp(la0[i][j] - r[i] - c_old) )
// Safe shift by c_old: after iteration 1 all args <= 0; iter-1 args <= ~28
// (exp <= 1.5e12, sum <= ~1.5e15, fine in f32). No max pass needed.
// Block: 256 threads = 16 cols x 16 row-groups (64 rows each) -> covers the
// full 1024-row column in one block (no cross-block combine needed).
// Grid: (N/16, S) = (64, 16) = 1024 blocks.
// ---------------------------------------------------------------------------
__global__ void __launch_bounds__(256)
col_pass(const float* __restrict__ u, const float* __restrict__ la,
         const float* __restrict__ r, float* __restrict__ c) {
    const int s  = blockIdx.y;
    const int t  = threadIdx.x;
    const int tx = t & 15;    // column within chunk
    const int rg = t >> 4;    // row group (64 rows each)
    const int j  = blockIdx.x * 16 + tx;

    __shared__ alignas(16) float r_lds[N_];
    ((float4*)r_lds)[t] = ((const float4*)(r + s * N_))[t];
    __syncthreads();

    const float cj = c[s * N_ + j];
    const float* up  = u + (size_t)s * N_ * N_;
    const int i0 = rg * 64;
    float acc = 0.f;
    #pragma unroll 4
    for (int ii = 0; ii < 64; ++ii) {
        const int i = i0 + ii;
        const float v = la0_of(up[(size_t)i * N_ + j], la[i * N_ + j]);
        acc += __expf(v - r_lds[i] - cj);
    }

    __shared__ float sums[16][17];
    sums[rg][tx] = acc;
    __syncthreads();
    if (t < 16) {  // tx == t, so `cj` in this thread belongs to column j
        float tot = 0.f;
        #pragma unroll
        for (int k = 0; k < 16; ++k) tot += sums[k][t];
        c[s * N_ + blockIdx.x * 16 + t] = cj + __logf(tot);
    }
}

// ---------------------------------------------------------------------------
// Row pass: r[s][i] = r_old + log( sum_j exp(la0[i][j] - c[j] - r_old) )
// Args are <= 0 always (c[j] >= la0[i][j] - r_old by construction).
// Block: 256 threads = 4 waves, one wave per row (contiguous coalesced reads).
// Grid: (N/4, S) = (256, 16) = 4096 blocks.
// ---------------------------------------------------------------------------
__global__ void __launch_bounds__(256)
row_pass(const float* __restrict__ u, const float* __restrict__ la,
         const float* __restrict__ c, float* __restrict__ r) {
    const int s = blockIdx.y;
    const int t = threadIdx.x;
    const int w = t >> 6;
    const int l = t & 63;
    const int i = blockIdx.x * 4 + w;

    __shared__ alignas(16) float c_lds[N_];
    ((float4*)c_lds)[t] = ((const float4*)(c + s * N_))[t];
    __syncthreads();

    const float ri = r[s * N_ + i];
    const float* up  = u  + (size_t)s * N_ * N_ + (size_t)i * N_;
    const float* lap = la + (size_t)i * N_;
    float acc = 0.f;
    #pragma unroll
    for (int k = 0; k < 16; ++k) {
        const int jj = l + (k << 6);
        const float v = la0_of(up[jj], lap[jj]);
        acc += __expf(v - c_lds[jj] - ri);
    }
    #pragma unroll
    for (int m = 32; m >= 1; m >>= 1) acc += __shfl_xor(acc, m);
    if (l == 0) r[s * N_ + i] = ri + __logf(acc);
}

// ---------------------------------------------------------------------------
// x (256x1024) -> xT (1024x256) so the GEMM A-operand reads are coalesced.
// ---------------------------------------------------------------------------
__global__ void __launch_bounds__(256)
transpose_x(const float* __restrict__ x, float* __restrict__ xT) {
    __shared__ float tile[32][33];
    const int tx = threadIdx.x;       // 32
    const int ty = threadIdx.y;       // 8
    const int gx = blockIdx.x * 32;   // n
    const int gy = blockIdx.y * 32;   // b
    #pragma unroll
    for (int i = 0; i < 4; ++i)
        tile[ty + i * 8][tx] = x[(gy + ty + i * 8) * N_ + gx + tx];
    __syncthreads();
    #pragma unroll
    for (int i = 0; i < 4; ++i)
        xT[(size_t)(gx + ty + i * 8) * B_ + gy + tx] = tile[tx][ty + i * 8];
}

// ---------------------------------------------------------------------------
// out[s][b][m] = exp(-c[m]) * sum_k x[b][k] * exp(la0[k][m] - r[k])
// (exp(-c_m) factored out of the K loop; la0 - r - c <= 0 post-Sinkhorn so
//  the staged exp(la0 - r_k) <= exp(c_m), sums stay well inside f32 range.)
// Block: 256 threads, BM=128 (ty: 32 groups x 4 rows), BN=64 (tx: 8 x 8 cols),
// BK=16. P-tile computed on the fly into LDS; A read from xT via L1.
// Grid: (N/64, B/128, S) = (16, 2, 16) = 512 blocks.
// ---------------------------------------------------------------------------
__global__ void __launch_bounds__(256)
matmul_out(const float* __restrict__ u, const float* __restrict__ la,
           const float* __restrict__ xT, const float* __restrict__ r,
           const float* __restrict__ c, float* __restrict__ out) {
    const int s  = blockIdx.z;
    const int m0 = blockIdx.x * 64;
    const int b0 = blockIdx.y * 128;
    const int t  = threadIdx.x;
    const int tx = t & 7;    // col group: cols m0 + tx*8 .. +8
    const int ty = t >> 3;   // row group: rows b0 + ty*4 .. +4

    __shared__ alignas(16) float Bs[16][64];
    float acc[4][8] = {};

    const float* up = u + (size_t)s * N_ * N_;
    const float* rp = r + s * N_;

    for (int k0 = 0; k0 < N_; k0 += 16) {
        __syncthreads();
        {   // stage P'[k][m] = exp(la0 - r[k]) for k in [k0,k0+16), m in tile
            const int kk = t >> 4;
            const int f4 = t & 15;
            const int k  = k0 + kk;
            const float rk = rp[k];
            const float4 uv = *(const float4*)(up + (size_t)k * N_ + m0 + f4 * 4);
            const float4 lv = *(const float4*)(la + (size_t)k * N_ + m0 + f4 * 4);
            float4 p;
            p.x = __expf(la0_of(uv.x, lv.x) - rk);
            p.y = __expf(la0_of(uv.y, lv.y) - rk);
            p.z = __expf(la0_of(uv.z, lv.z) - rk);
            p.w = __expf(la0_of(uv.w, lv.w) - rk);
            *(float4*)(&Bs[kk][f4 * 4]) = p;
        }
        __syncthreads();
        #pragma unroll
        for (int kk = 0; kk < 16; ++kk) {
            const float4 a4 = *(const float4*)(xT + (size_t)(k0 + kk) * B_ + b0 + ty * 4);
            const float4 bA = *(const float4*)(&Bs[kk][tx * 8]);
            const float4 bB = *(const float4*)(&Bs[kk][tx * 8 + 4]);
            const float av[4] = {a4.x, a4.y, a4.z, a4.w};
            const float bv[8] = {bA.x, bA.y, bA.z, bA.w, bB.x, bB.y, bB.z, bB.w};
            #pragma unroll
            for (int rr = 0; rr < 4; ++rr)
                #pragma unroll
                for (int cc = 0; cc < 8; ++cc)
                    acc[rr][cc] += av[rr] * bv[cc];
        }
    }

    float cm[8];
    #pragma unroll
    for (int cc = 0; cc < 8; ++cc) cm[cc] = __expf(-c[s * N_ + m0 + tx * 8 + cc]);
    #pragma unroll
    for (int rr = 0; rr < 4; ++rr) {
        float4 o0, o1;
        o0.x = acc[rr][0] * cm[0]; o0.y = acc[rr][1] * cm[1];
        o0.z = acc[rr][2] * cm[2]; o0.w = acc[rr][3] * cm[3];
        o1.x = acc[rr][4] * cm[4]; o1.y = acc[rr][5] * cm[5];
        o1.z = acc[rr][6] * cm[6]; o1.w = acc[rr][7] * cm[7];
        float* op = out + ((size_t)s * B_ + b0 + ty * 4 + rr) * N_ + m0 + tx * 8;
        *(float4*)op       = o0;
        *(float4*)(op + 4) = o1;
    }
}

extern "C" void kernel_launch(void* const* d_in, const int* in_sizes, int n_in,
                              void* d_out, int out_size, void* d_ws, size_t ws_size,
                              hipStream_t stream) {
    (void)in_sizes; (void)n_in; (void)out_size; (void)ws_size;
    const float* x  = (const float*)d_in[0];   // (256, 1024)
    const float* la = (const float*)d_in[1];   // (1024, 1024)
    const float* u  = (const float*)d_in[2];   // (16, 1024, 1024)
    float* out = (float*)d_out;                // (16, 256, 1024) f32

    // Workspace layout (needs 1.125 MiB): r (64 KB) | c (64 KB) | xT (1 MiB)
    float* r  = (float*)d_ws;
    float* c  = r + S_ * N_;
    float* xT = c + S_ * N_;

    // r = c = 0 (must be re-zeroed every call: deterministic launches)
    hipMemsetAsync(d_ws, 0, 2 * S_ * N_ * sizeof(float), stream);
    transpose_x<<<dim3(N_ / 32, B_ / 32), dim3(32, 8), 0, stream>>>(x, xT);

    for (int it = 0; it < ITERS; ++it) {
        col_pass<<<dim3(N_ / 16, S_), 256, 0, stream>>>(u, la, r, c);
        row_pass<<<dim3(N_ / 4, S_),  256, 0, stream>>>(u, la, c, r);
    }

    matmul_out<<<dim3(N_ / 64, B_ / 128, S_), 256, 0, stream>>>(u, la, xT, r, c, out);
}

// Round 2
// 452.827 us; speedup vs baseline: 2.7646x; 2.7646x over previous
//
#include <hip/hip_runtime.h>
#include <math.h>

// Problem constants (fixed by the reference: B=256, N=1024, S=16, 21 iters)
static constexpr int S_ = 16;
static constexpr int N_ = 1024;
static constexpr int B_ = 256;
static constexpr int ITERS = 21;
#define EPSC 1e-10f

// ---------------- bf16 helpers (raw ushort bits) ----------------
__device__ __forceinline__ float bf2f(unsigned short h) {
    union { unsigned int u; float f; } v; v.u = ((unsigned int)h) << 16; return v.f;
}
__device__ __forceinline__ unsigned short f2bf(float f) {
    union { float f; unsigned int u; } v; v.f = f;
    unsigned int r = v.u + 0x7fffu + ((v.u >> 16) & 1u);   // round-nearest-even
    return (unsigned short)(r >> 16);
}

// la0 = log_alpha + gumbel_noise(u), noise = -log(EPS - log(u + EPS)).
__device__ __forceinline__ float la0_of(float uv, float lav) {
    float t1 = __logf(uv + EPSC);
    float t2 = EPSC - t1;
    return lav - __logf(t2);
}

// ===========================================================================
// FAST PATH: linear-space Sinkhorn on precomputed bf16 kernel matrix
//   K[s][k][m] = exp(la + noise) = exp(la) / (EPS - log(u + EPS))
//   col pass: V_j = 1 / sum_i K[i][j] * U_i    (uses KbT, row-major in j)
//   row pass: U_i = 1 / sum_j K[i][j] * V_j    (uses Kb)
//   out[s][b][m] = V_m * sum_k (x[b][k]*U_k) * K[k][m]
// ===========================================================================

// K build: grid-stride over 8-element chunks. 96 MB traffic, ~20 us.
__global__ void __launch_bounds__(256)
build_K(const float* __restrict__ u, const float* __restrict__ la,
        unsigned short* __restrict__ Kb) {
    const size_t total8 = (size_t)S_ * N_ * N_ / 8;
    for (size_t idx = (size_t)blockIdx.x * 256 + threadIdx.x; idx < total8;
         idx += (size_t)gridDim.x * 256) {
        const size_t e0 = idx * 8;
        const size_t lo = e0 & (size_t)(N_ * N_ - 1);
        float4 u0 = *(const float4*)(u + e0);
        float4 u1 = *(const float4*)(u + e0 + 4);
        float4 l0 = *(const float4*)(la + lo);
        float4 l1 = *(const float4*)(la + lo + 4);
        const float uf[8] = {u0.x, u0.y, u0.z, u0.w, u1.x, u1.y, u1.z, u1.w};
        const float lf[8] = {l0.x, l0.y, l0.z, l0.w, l1.x, l1.y, l1.z, l1.w};
        unsigned int w[4];
        #pragma unroll
        for (int e = 0; e < 4; ++e) {
            float k0 = __expf(lf[2 * e])     / (EPSC - __logf(uf[2 * e] + EPSC));
            float k1 = __expf(lf[2 * e + 1]) / (EPSC - __logf(uf[2 * e + 1] + EPSC));
            w[e] = (unsigned int)f2bf(k0) | ((unsigned int)f2bf(k1) << 16);
        }
        *(uint4*)(Kb + e0) = make_uint4(w[0], w[1], w[2], w[3]);
    }
}

// bf16 transpose per sample: KbT[s][m][k] = Kb[s][k][m]. 64x64 tiles.
__global__ void __launch_bounds__(256)
transpose_K(const unsigned short* __restrict__ Kb, unsigned short* __restrict__ KbT) {
    const int s = blockIdx.z, k0 = blockIdx.x * 64, m0 = blockIdx.y * 64;
    __shared__ unsigned short tile[64][66];
    const int t = threadIdx.x, c4 = (t & 15) * 4, rr = t >> 4;
    const unsigned short* src = Kb + (size_t)s * N_ * N_;
    unsigned short* dst = KbT + (size_t)s * N_ * N_;
    #pragma unroll
    for (int q = 0; q < 4; ++q) {
        const int r = q * 16 + rr;
        ushort4 v = *(const ushort4*)(src + (size_t)(k0 + r) * N_ + m0 + c4);
        tile[r][c4] = v.x; tile[r][c4 + 1] = v.y; tile[r][c4 + 2] = v.z; tile[r][c4 + 3] = v.w;
    }
    __syncthreads();
    #pragma unroll
    for (int q = 0; q < 4; ++q) {
        const int rm = q * 16 + rr;
        ushort4 v;
        v.x = tile[c4][rm]; v.y = tile[c4 + 1][rm];
        v.z = tile[c4 + 2][rm]; v.w = tile[c4 + 3][rm];
        *(ushort4*)(dst + (size_t)(m0 + rm) * N_ + k0 + c4) = v;
    }
}

__global__ void __launch_bounds__(256)
init_ones(float* __restrict__ p) {
    ((float4*)p)[blockIdx.x * 256 + threadIdx.x] = make_float4(1.f, 1.f, 1.f, 1.f);
}

// One normalization pass: wout[i] = 1 / sum_j M[s][i][j] * win[j].
// 4 waves/block, one row per wave, fully coalesced bf16 streaming.
__global__ void __launch_bounds__(256)
pass_lin(const unsigned short* __restrict__ M, const float* __restrict__ win,
         float* __restrict__ wout) {
    const int s = blockIdx.y;
    const int t = threadIdx.x;
    __shared__ alignas(16) float w_lds[N_];
    ((float4*)w_lds)[t] = ((const float4*)(win + s * N_))[t];
    __syncthreads();
    const int wv = t >> 6, l = t & 63;
    const int i = blockIdx.x * 4 + wv;
    const unsigned short* row = M + ((size_t)s * N_ + i) * N_;
    float acc = 0.f;
    #pragma unroll
    for (int q = 0; q < 4; ++q) {
        uint2 kk = *(const uint2*)(row + q * 256 + l * 4);
        float4 w4 = ((const float4*)w_lds)[q * 64 + l];
        acc += bf2f((unsigned short)(kk.x & 0xffffu)) * w4.x;
        acc += bf2f((unsigned short)(kk.x >> 16))     * w4.y;
        acc += bf2f((unsigned short)(kk.y & 0xffffu)) * w4.z;
        acc += bf2f((unsigned short)(kk.y >> 16))     * w4.w;
    }
    #pragma unroll
    for (int m = 32; m >= 1; m >>= 1) acc += __shfl_xor(acc, m);
    if (l == 0) wout[s * N_ + i] = 1.0f / acc;
}

// out[s][b][m] = V_m * sum_k (x[b][k]*U_k) * K[k][m]
// 64x64 tile, 4x4 per thread, BK=32, both operands staged in LDS.
// Grid (16, 4, 16) = 1024 blocks -> 4 blocks/CU, 4 waves/SIMD.
__global__ void __launch_bounds__(256)
matmul_lin(const unsigned short* __restrict__ Kb, const float* __restrict__ xT,
           const float* __restrict__ U, const float* __restrict__ V,
           float* __restrict__ out) {
    const int s = blockIdx.z, m0 = blockIdx.x * 64, b0 = blockIdx.y * 64;
    const int t = threadIdx.x, tx = t & 15, ty = t >> 4;
    __shared__ alignas(16) float As[32][64];   // (k, b), x*U folded in
    __shared__ alignas(16) float Bs[32][64];   // (k, m)
    float acc[4][4] = {};
    const unsigned short* kp = Kb + (size_t)s * N_ * N_;
    const float* up = U + s * N_;

    for (int k0 = 0; k0 < N_; k0 += 32) {
        __syncthreads();
        #pragma unroll
        for (int q = 0; q < 2; ++q) {
            const int kk = q * 16 + ty;
            const float uk = up[k0 + kk];
            float4 a = *(const float4*)(xT + (size_t)(k0 + kk) * B_ + b0 + tx * 4);
            a.x *= uk; a.y *= uk; a.z *= uk; a.w *= uk;
            *(float4*)&As[kk][tx * 4] = a;
            ushort4 kv = *(const ushort4*)(kp + (size_t)(k0 + kk) * N_ + m0 + tx * 4);
            float4 b = make_float4(bf2f(kv.x), bf2f(kv.y), bf2f(kv.z), bf2f(kv.w));
            *(float4*)&Bs[kk][tx * 4] = b;
        }
        __syncthreads();
        #pragma unroll
        for (int kk = 0; kk < 32; ++kk) {
            float4 a4 = *(const float4*)&As[kk][ty * 4];
            float4 b4 = *(const float4*)&Bs[kk][tx * 4];
            const float av[4] = {a4.x, a4.y, a4.z, a4.w};
            const float bv[4] = {b4.x, b4.y, b4.z, b4.w};
            #pragma unroll
            for (int r = 0; r < 4; ++r)
                #pragma unroll
                for (int c = 0; c < 4; ++c)
                    acc[r][c] += av[r] * bv[c];
        }
    }

    float4 v4 = *(const float4*)(V + s * N_ + m0 + tx * 4);
    const float vv[4] = {v4.x, v4.y, v4.z, v4.w};
    #pragma unroll
    for (int r = 0; r < 4; ++r) {
        float4 o;
        o.x = acc[r][0] * vv[0]; o.y = acc[r][1] * vv[1];
        o.z = acc[r][2] * vv[2]; o.w = acc[r][3] * vv[3];
        *(float4*)(out + ((size_t)s * B_ + b0 + ty * 4 + r) * N_ + m0 + tx * 4) = o;
    }
}

// x (256x1024) -> xT (1024x256), shared by both paths.
__global__ void __launch_bounds__(256)
transpose_x(const float* __restrict__ x, float* __restrict__ xT) {
    __shared__ float tile[32][33];
    const int tx = threadIdx.x, ty = threadIdx.y;
    const int gx = blockIdx.x * 32, gy = blockIdx.y * 32;
    #pragma unroll
    for (int i = 0; i < 4; ++i)
        tile[ty + i * 8][tx] = x[(gy + ty + i * 8) * N_ + gx + tx];
    __syncthreads();
    #pragma unroll
    for (int i = 0; i < 4; ++i)
        xT[(size_t)(gx + ty + i * 8) * B_ + gy + tx] = tile[tx][ty + i * 8];
}

// ===========================================================================
// FALLBACK PATH (round-1 proven kernels) — used only if ws is too small.
// ===========================================================================
__global__ void __launch_bounds__(256)
col_pass(const float* __restrict__ u, const float* __restrict__ la,
         const float* __restrict__ r, float* __restrict__ c) {
    const int s = blockIdx.y, t = threadIdx.x;
    const int tx = t & 15, rg = t >> 4;
    const int j = blockIdx.x * 16 + tx;
    __shared__ alignas(16) float r_lds[N_];
    ((float4*)r_lds)[t] = ((const float4*)(r + s * N_))[t];
    __syncthreads();
    const float cj = c[s * N_ + j];
    const float* up = u + (size_t)s * N_ * N_;
    const int i0 = rg * 64;
    float acc = 0.f;
    #pragma unroll 4
    for (int ii = 0; ii < 64; ++ii) {
        const int i = i0 + ii;
        const float v = la0_of(up[(size_t)i * N_ + j], la[i * N_ + j]);
        acc += __expf(v - r_lds[i] - cj);
    }
    __shared__ float sums[16][17];
    sums[rg][tx] = acc;
    __syncthreads();
    if (t < 16) {
        float tot = 0.f;
        #pragma unroll
        for (int k = 0; k < 16; ++k) tot += sums[k][t];
        c[s * N_ + blockIdx.x * 16 + t] = cj + __logf(tot);
    }
}

__global__ void __launch_bounds__(256)
row_pass(const float* __restrict__ u, const float* __restrict__ la,
         const float* __restrict__ c, float* __restrict__ r) {
    const int s = blockIdx.y, t = threadIdx.x;
    const int w = t >> 6, l = t & 63;
    const int i = blockIdx.x * 4 + w;
    __shared__ alignas(16) float c_lds[N_];
    ((float4*)c_lds)[t] = ((const float4*)(c + s * N_))[t];
    __syncthreads();
    const float ri = r[s * N_ + i];
    const float* up = u + (size_t)s * N_ * N_ + (size_t)i * N_;
    const float* lap = la + (size_t)i * N_;
    float acc = 0.f;
    #pragma unroll
    for (int k = 0; k < 16; ++k) {
        const int jj = l + (k << 6);
        acc += __expf(la0_of(up[jj], lap[jj]) - c_lds[jj] - ri);
    }
    #pragma unroll
    for (int m = 32; m >= 1; m >>= 1) acc += __shfl_xor(acc, m);
    if (l == 0) r[s * N_ + i] = ri + __logf(acc);
}

__global__ void __launch_bounds__(256)
matmul_out(const float* __restrict__ u, const float* __restrict__ la,
           const float* __restrict__ xT, const float* __restrict__ r,
           const float* __restrict__ c, float* __restrict__ out) {
    const int s = blockIdx.z, m0 = blockIdx.x * 64, b0 = blockIdx.y * 128;
    const int t = threadIdx.x, tx = t & 7, ty = t >> 3;
    __shared__ alignas(16) float Bs[16][64];
    float acc[4][8] = {};
    const float* up = u + (size_t)s * N_ * N_;
    const float* rp = r + s * N_;
    for (int k0 = 0; k0 < N_; k0 += 16) {
        __syncthreads();
        {
            const int kk = t >> 4, f4 = t & 15;
            const int k = k0 + kk;
            const float rk = rp[k];
            const float4 uv = *(const float4*)(up + (size_t)k * N_ + m0 + f4 * 4);
            const float4 lv = *(const float4*)(la + (size_t)k * N_ + m0 + f4 * 4);
            float4 p;
            p.x = __expf(la0_of(uv.x, lv.x) - rk);
            p.y = __expf(la0_of(uv.y, lv.y) - rk);
            p.z = __expf(la0_of(uv.z, lv.z) - rk);
            p.w = __expf(la0_of(uv.w, lv.w) - rk);
            *(float4*)(&Bs[kk][f4 * 4]) = p;
        }
        __syncthreads();
        #pragma unroll
        for (int kk = 0; kk < 16; ++kk) {
            const float4 a4 = *(const float4*)(xT + (size_t)(k0 + kk) * B_ + b0 + ty * 4);
            const float4 bA = *(const float4*)(&Bs[kk][tx * 8]);
            const float4 bB = *(const float4*)(&Bs[kk][tx * 8 + 4]);
            const float av[4] = {a4.x, a4.y, a4.z, a4.w};
            const float bv[8] = {bA.x, bA.y, bA.z, bA.w, bB.x, bB.y, bB.z, bB.w};
            #pragma unroll
            for (int rr = 0; rr < 4; ++rr)
                #pragma unroll
                for (int cc = 0; cc < 8; ++cc)
                    acc[rr][cc] += av[rr] * bv[cc];
        }
    }
    float cm[8];
    #pragma unroll
    for (int cc = 0; cc < 8; ++cc) cm[cc] = __expf(-c[s * N_ + m0 + tx * 8 + cc]);
    #pragma unroll
    for (int rr = 0; rr < 4; ++rr) {
        float4 o0, o1;
        o0.x = acc[rr][0] * cm[0]; o0.y = acc[rr][1] * cm[1];
        o0.z = acc[rr][2] * cm[2]; o0.w = acc[rr][3] * cm[3];
        o1.x = acc[rr][4] * cm[4]; o1.y = acc[rr][5] * cm[5];
        o1.z = acc[rr][6] * cm[6]; o1.w = acc[rr][7] * cm[7];
        float* op = out + ((size_t)s * B_ + b0 + ty * 4 + rr) * N_ + m0 + tx * 8;
        *(float4*)op       = o0;
        *(float4*)(op + 4) = o1;
    }
}

// ===========================================================================
extern "C" void kernel_launch(void* const* d_in, const int* in_sizes, int n_in,
                              void* d_out, int out_size, void* d_ws, size_t ws_size,
                              hipStream_t stream) {
    (void)in_sizes; (void)n_in; (void)out_size;
    const float* x  = (const float*)d_in[0];   // (256, 1024)
    const float* la = (const float*)d_in[1];   // (1024, 1024)
    const float* u  = (const float*)d_in[2];   // (16, 1024, 1024)
    float* out = (float*)d_out;                // (16, 256, 1024) f32

    const size_t KN = (size_t)S_ * N_ * N_;            // 16.8M elems
    const size_t need = KN * 2 * 2                     // Kb + KbT (bf16)
                      + (size_t)2 * S_ * N_ * 4        // U, V
                      + (size_t)N_ * B_ * 4;           // xT

    if (ws_size >= need) {
        // ---------------- fast path ----------------
        unsigned short* Kb  = (unsigned short*)d_ws;
        unsigned short* KbT = Kb + KN;
        float* U  = (float*)(KbT + KN);
        float* V  = U + S_ * N_;
        float* xT = V + S_ * N_;

        build_K<<<2048, 256, 0, stream>>>(u, la, Kb);
        transpose_K<<<dim3(16, 16, 16), 256, 0, stream>>>(Kb, KbT);
        init_ones<<<S_ * N_ / 1024, 256, 0, stream>>>(U);
        transpose_x<<<dim3(N_ / 32, B_ / 32), dim3(32, 8), 0, stream>>>(x, xT);

        for (int it = 0; it < ITERS; ++it) {
            pass_lin<<<dim3(N_ / 4, S_), 256, 0, stream>>>(KbT, U, V);  // col norm
            pass_lin<<<dim3(N_ / 4, S_), 256, 0, stream>>>(Kb,  V, U);  // row norm
        }
        matmul_lin<<<dim3(N_ / 64, B_ / 64, S_), 256, 0, stream>>>(Kb, xT, U, V, out);
    } else {
        // ---------------- fallback: round-1 proven path ----------------
        float* r  = (float*)d_ws;
        float* c  = r + S_ * N_;
        float* xT = c + S_ * N_;
        hipMemsetAsync(d_ws, 0, 2 * S_ * N_ * sizeof(float), stream);
        transpose_x<<<dim3(N_ / 32, B_ / 32), dim3(32, 8), 0, stream>>>(x, xT);
        for (int it = 0; it < ITERS; ++it) {
            col_pass<<<dim3(N_ / 16, S_), 256, 0, stream>>>(u, la, r, c);
            row_pass<<<dim3(N_ / 4, S_),  256, 0, stream>>>(u, la, c, r);
        }
        matmul_out<<<dim3(N_ / 64, B_ / 128, S_), 256, 0, stream>>>(u, la, xT, r, c, out);
    }
}

// Round 4
// 364.073 us; speedup vs baseline: 3.4386x; 1.2438x over previous
//
#include <hip/hip_runtime.h>
#include <math.h>

// Problem constants (fixed by the reference: B=256, N=1024, S=16, 21 iters)
static constexpr int S_ = 16;
static constexpr int N_ = 1024;
static constexpr int B_ = 256;
static constexpr int ITERS = 21;
#define EPSC 1e-10f

using short8 = __attribute__((ext_vector_type(8))) short;
using f32x4  = __attribute__((ext_vector_type(4))) float;

// ---------------- bf16 helpers (raw ushort bits) ----------------
__device__ __forceinline__ float bf2f(unsigned short h) {
    union { unsigned int u; float f; } v; v.u = ((unsigned int)h) << 16; return v.f;
}
__device__ __forceinline__ unsigned short f2bf(float f) {
    union { float f; unsigned int u; } v; v.f = f;
    unsigned int r = v.u + 0x7fffu + ((v.u >> 16) & 1u);   // round-nearest-even
    return (unsigned short)(r >> 16);
}
__device__ __forceinline__ unsigned int pack2(float a, float b) {
    return (unsigned int)f2bf(a) | ((unsigned int)f2bf(b) << 16);
}

// la0 = log_alpha + gumbel_noise(u), noise = -log(EPS - log(u + EPS)).
__device__ __forceinline__ float la0_of(float uv, float lav) {
    float t1 = __logf(uv + EPSC);
    float t2 = EPSC - t1;
    return lav - __logf(t2);
}

// ===========================================================================
// FAST PATH: linear-space Sinkhorn on precomputed bf16 kernel matrix
//   K[s][k][m] = exp(la)/(EPS - log(u+EPS));  KbT = per-sample transpose
//   col pass: V_j = 1 / sum_i K[i][j] U_i   (KbT);  row: U_i = 1/sum_j K V_j
//   out[s][b][m] = V_m * sum_k (x[b][k]*U_k) * K[k][m]   (bf16 MFMA)
// ===========================================================================

__global__ void __launch_bounds__(256)
build_K(const float* __restrict__ u, const float* __restrict__ la,
        unsigned short* __restrict__ Kb) {
    const size_t total8 = (size_t)S_ * N_ * N_ / 8;
    for (size_t idx = (size_t)blockIdx.x * 256 + threadIdx.x; idx < total8;
         idx += (size_t)gridDim.x * 256) {
        const size_t e0 = idx * 8;
        const size_t lo = e0 & (size_t)(N_ * N_ - 1);
        float4 u0 = *(const float4*)(u + e0);
        float4 u1 = *(const float4*)(u + e0 + 4);
        float4 l0 = *(const float4*)(la + lo);
        float4 l1 = *(const float4*)(la + lo + 4);
        const float uf[8] = {u0.x, u0.y, u0.z, u0.w, u1.x, u1.y, u1.z, u1.w};
        const float lf[8] = {l0.x, l0.y, l0.z, l0.w, l1.x, l1.y, l1.z, l1.w};
        unsigned int w[4];
        #pragma unroll
        for (int e = 0; e < 4; ++e) {
            float k0 = __expf(lf[2 * e])     / (EPSC - __logf(uf[2 * e] + EPSC));
            float k1 = __expf(lf[2 * e + 1]) / (EPSC - __logf(uf[2 * e + 1] + EPSC));
            w[e] = (unsigned int)f2bf(k0) | ((unsigned int)f2bf(k1) << 16);
        }
        *(uint4*)(Kb + e0) = make_uint4(w[0], w[1], w[2], w[3]);
    }
}

__global__ void __launch_bounds__(256)
transpose_K(const unsigned short* __restrict__ Kb, unsigned short* __restrict__ KbT) {
    const int s = blockIdx.z, k0 = blockIdx.x * 64, m0 = blockIdx.y * 64;
    __shared__ unsigned short tile[64][66];
    const int t = threadIdx.x, c4 = (t & 15) * 4, rr = t >> 4;
    const unsigned short* src = Kb + (size_t)s * N_ * N_;
    unsigned short* dst = KbT + (size_t)s * N_ * N_;
    #pragma unroll
    for (int q = 0; q < 4; ++q) {
        const int r = q * 16 + rr;
        ushort4 v = *(const ushort4*)(src + (size_t)(k0 + r) * N_ + m0 + c4);
        tile[r][c4] = v.x; tile[r][c4 + 1] = v.y; tile[r][c4 + 2] = v.z; tile[r][c4 + 3] = v.w;
    }
    __syncthreads();
    #pragma unroll
    for (int q = 0; q < 4; ++q) {
        const int rm = q * 16 + rr;
        ushort4 v;
        v.x = tile[c4][rm]; v.y = tile[c4 + 1][rm];
        v.z = tile[c4 + 2][rm]; v.w = tile[c4 + 3][rm];
        *(ushort4*)(dst + (size_t)(m0 + rm) * N_ + k0 + c4) = v;
    }
}

__global__ void __launch_bounds__(256)
init_ones(float* __restrict__ p) {
    ((float4*)p)[blockIdx.x * 256 + threadIdx.x] = make_float4(1.f, 1.f, 1.f, 1.f);
}

__device__ __forceinline__ float dot8(uint4 k, const float4& a, const float4& b) {
    return bf2f((unsigned short)(k.x & 0xffffu)) * a.x
         + bf2f((unsigned short)(k.x >> 16))     * a.y
         + bf2f((unsigned short)(k.y & 0xffffu)) * a.z
         + bf2f((unsigned short)(k.y >> 16))     * a.w
         + bf2f((unsigned short)(k.z & 0xffffu)) * b.x
         + bf2f((unsigned short)(k.z >> 16))     * b.y
         + bf2f((unsigned short)(k.w & 0xffffu)) * b.z
         + bf2f((unsigned short)(k.w >> 16))     * b.w;
}

// wout[i] = 1 / sum_j M[s][i][j] * win[j].  2 rows/wave, dwordx4 K loads
// (64B/lane in flight).  win is read directly from global (4KB/sample,
// L1/L2-hot, each lane reads its own 32B chunks) — no LDS, no barrier.
// (Round-3 bug: the LDS slot-shift j -> j + 4*((j>>5)&1) was NON-BIJECTIVE,
//  elements 60..63 collided with 64..67. Global reads sidestep it entirely.)
__global__ void __launch_bounds__(256)
pass_lin2(const unsigned short* __restrict__ M, const float* __restrict__ win,
          float* __restrict__ wout) {
    const int s = blockIdx.y;
    const int t = threadIdx.x;
    const int wv = t >> 6, l = t & 63;
    const int i0 = blockIdx.x * 8 + wv * 2;
    const float* wp = win + s * N_ + l * 8;
    const float4 w0a = *(const float4*)(wp);
    const float4 w0b = *(const float4*)(wp + 4);
    const float4 w1a = *(const float4*)(wp + 512);
    const float4 w1b = *(const float4*)(wp + 516);
    const unsigned short* base = M + ((size_t)s * N_ + i0) * N_ + l * 8;
    uint4 k0a = *(const uint4*)(base);
    uint4 k0b = *(const uint4*)(base + 512);
    uint4 k1a = *(const uint4*)(base + N_);
    uint4 k1b = *(const uint4*)(base + N_ + 512);
    float acc0 = dot8(k0a, w0a, w0b) + dot8(k0b, w1a, w1b);
    float acc1 = dot8(k1a, w0a, w0b) + dot8(k1b, w1a, w1b);
    #pragma unroll
    for (int m = 32; m >= 1; m >>= 1) {
        acc0 += __shfl_xor(acc0, m);
        acc1 += __shfl_xor(acc1, m);
    }
    if (l == 0) {
        wout[s * N_ + i0]     = 1.0f / acc0;
        wout[s * N_ + i0 + 1] = 1.0f / acc1;
    }
}

// out[s][b][m] = V_m * sum_k (x[b][k]*U_k) * K[k][m], bf16 MFMA 16x16x32.
// BM=128 (b), BN=64 (m), BK=64. A staged from f32 x (bf16 on the fly);
// B staged from KbT rows (contiguous k) with U folded in. XOR-swizzled LDS.
// 4 waves: wave tile 64(b) x 32(m) = 4x2 fragments. Grid (16,2,16)=512.
__global__ void __launch_bounds__(256)
mfma_out(const float* __restrict__ x, const unsigned short* __restrict__ KbT,
         const float* __restrict__ U, const float* __restrict__ V,
         float* __restrict__ out) {
    const int s  = blockIdx.z;
    const int m0 = blockIdx.x * 64;
    const int b0 = blockIdx.y * 128;
    const int t  = threadIdx.x;
    const int wid = t >> 6, l = t & 63;
    const int wr = wid >> 1, wc = wid & 1;

    __shared__ alignas(16) unsigned short lsA[128 * 64];  // [b][k] swizzled
    __shared__ alignas(16) unsigned short lsB[64 * 64];   // [m][k] swizzled, U folded

    f32x4 acc[4][2];
    #pragma unroll
    for (int fi = 0; fi < 4; ++fi)
        #pragma unroll
        for (int fj = 0; fj < 2; ++fj)
            acc[fi][fj] = (f32x4){0.f, 0.f, 0.f, 0.f};

    const unsigned short* Bp = KbT + ((size_t)s * N_ + m0) * N_;
    const float* Up = U + s * N_;

    for (int k0 = 0; k0 < N_; k0 += 64) {
        __syncthreads();
        // ---- stage A tile: 128 rows x 64 k (16KB), f32 x -> bf16 ----
        #pragma unroll
        for (int i = 0; i < 4; ++i) {
            const int Lb  = i * 4096 + t * 16;
            const int row = Lb >> 7;
            const int kb  = Lb & 127;
            const float* xp = x + (size_t)(b0 + row) * N_ + k0 + (kb >> 1);
            float4 xa = *(const float4*)xp;
            float4 xb = *(const float4*)(xp + 4);
            uint4 pk = make_uint4(pack2(xa.x, xa.y), pack2(xa.z, xa.w),
                                  pack2(xb.x, xb.y), pack2(xb.z, xb.w));
            *(uint4*)((char*)lsA + (row << 7) + (kb ^ ((row & 7) << 4))) = pk;
        }
        // ---- stage B tile: 64 rows (m) x 64 k (8KB), KbT * U[k] -> bf16 ----
        #pragma unroll
        for (int i = 0; i < 2; ++i) {
            const int Lb  = i * 4096 + t * 16;
            const int row = Lb >> 7;
            const int kb  = Lb & 127;
            const int ke  = k0 + (kb >> 1);
            uint4 kv = *(const uint4*)((const char*)Bp + (size_t)row * 2048 + (k0 << 1) + kb);
            float4 u0 = *(const float4*)(Up + ke);
            float4 u1 = *(const float4*)(Up + ke + 4);
            uint4 pk;
            pk.x = pack2(bf2f((unsigned short)(kv.x & 0xffffu)) * u0.x,
                         bf2f((unsigned short)(kv.x >> 16))     * u0.y);
            pk.y = pack2(bf2f((unsigned short)(kv.y & 0xffffu)) * u0.z,
                         bf2f((unsigned short)(kv.y >> 16))     * u0.w);
            pk.z = pack2(bf2f((unsigned short)(kv.z & 0xffffu)) * u1.x,
                         bf2f((unsigned short)(kv.z >> 16))     * u1.y);
            pk.w = pack2(bf2f((unsigned short)(kv.w & 0xffffu)) * u1.z,
                         bf2f((unsigned short)(kv.w >> 16))     * u1.w);
            *(uint4*)((char*)lsB + (row << 7) + (kb ^ ((row & 7) << 4))) = pk;
        }
        __syncthreads();
        // ---- MFMA: fragment k = ks*32 + (l>>4)*8 + e, row index = l&15 ----
        #pragma unroll
        for (int ks = 0; ks < 2; ++ks) {
            const int koff = ks * 64 + ((l >> 4) << 4);   // byte offset in row
            short8 afr[4], bfr[2];
            #pragma unroll
            for (int fi = 0; fi < 4; ++fi) {
                const int r = wr * 64 + fi * 16 + (l & 15);
                afr[fi] = *(const short8*)((const char*)lsA + (r << 7) + (koff ^ ((r & 7) << 4)));
            }
            #pragma unroll
            for (int fj = 0; fj < 2; ++fj) {
                const int r = wc * 32 + fj * 16 + (l & 15);
                bfr[fj] = *(const short8*)((const char*)lsB + (r << 7) + (koff ^ ((r & 7) << 4)));
            }
            #pragma unroll
            for (int fi = 0; fi < 4; ++fi)
                #pragma unroll
                for (int fj = 0; fj < 2; ++fj)
                    acc[fi][fj] = __builtin_amdgcn_mfma_f32_16x16x32_bf16(
                        afr[fi], bfr[fj], acc[fi][fj], 0, 0, 0);
        }
    }
    // ---- epilogue: D[i][j]: col j = l&15, row i = 4*(l>>4)+e; scale by V ----
    #pragma unroll
    for (int fj = 0; fj < 2; ++fj) {
        const int m = m0 + wc * 32 + fj * 16 + (l & 15);
        const float vm = V[s * N_ + m];
        #pragma unroll
        for (int fi = 0; fi < 4; ++fi) {
            const int b = b0 + wr * 64 + fi * 16 + ((l >> 4) << 2);
            float* op = out + ((size_t)s * B_ + b) * N_ + m;
            #pragma unroll
            for (int e = 0; e < 4; ++e)
                op[(size_t)e * N_] = acc[fi][fj][e] * vm;
        }
    }
}

// x (256x1024) -> xT (1024x256)  [fallback path only]
__global__ void __launch_bounds__(256)
transpose_x(const float* __restrict__ x, float* __restrict__ xT) {
    __shared__ float tile[32][33];
    const int tx = threadIdx.x, ty = threadIdx.y;
    const int gx = blockIdx.x * 32, gy = blockIdx.y * 32;
    #pragma unroll
    for (int i = 0; i < 4; ++i)
        tile[ty + i * 8][tx] = x[(gy + ty + i * 8) * N_ + gx + tx];
    __syncthreads();
    #pragma unroll
    for (int i = 0; i < 4; ++i)
        xT[(size_t)(gx + ty + i * 8) * B_ + gy + tx] = tile[tx][ty + i * 8];
}

// ===========================================================================
// FALLBACK PATH (round-1 proven kernels) — used only if ws is too small.
// ===========================================================================
__global__ void __launch_bounds__(256)
col_pass(const float* __restrict__ u, const float* __restrict__ la,
         const float* __restrict__ r, float* __restrict__ c) {
    const int s = blockIdx.y, t = threadIdx.x;
    const int tx = t & 15, rg = t >> 4;
    const int j = blockIdx.x * 16 + tx;
    __shared__ alignas(16) float r_lds[N_];
    ((float4*)r_lds)[t] = ((const float4*)(r + s * N_))[t];
    __syncthreads();
    const float cj = c[s * N_ + j];
    const float* up = u + (size_t)s * N_ * N_;
    const int i0 = rg * 64;
    float acc = 0.f;
    #pragma unroll 4
    for (int ii = 0; ii < 64; ++ii) {
        const int i = i0 + ii;
        acc += __expf(la0_of(up[(size_t)i * N_ + j], la[i * N_ + j]) - r_lds[i] - cj);
    }
    __shared__ float sums[16][17];
    sums[rg][tx] = acc;
    __syncthreads();
    if (t < 16) {
        float tot = 0.f;
        #pragma unroll
        for (int k = 0; k < 16; ++k) tot += sums[k][t];
        c[s * N_ + blockIdx.x * 16 + t] = cj + __logf(tot);
    }
}

__global__ void __launch_bounds__(256)
row_pass(const float* __restrict__ u, const float* __restrict__ la,
         const float* __restrict__ c, float* __restrict__ r) {
    const int s = blockIdx.y, t = threadIdx.x;
    const int w = t >> 6, l = t & 63;
    const int i = blockIdx.x * 4 + w;
    __shared__ alignas(16) float c_lds[N_];
    ((float4*)c_lds)[t] = ((const float4*)(c + s * N_))[t];
    __syncthreads();
    const float ri = r[s * N_ + i];
    const float* up = u + (size_t)s * N_ * N_ + (size_t)i * N_;
    const float* lap = la + (size_t)i * N_;
    float acc = 0.f;
    #pragma unroll
    for (int k = 0; k < 16; ++k) {
        const int jj = l + (k << 6);
        acc += __expf(la0_of(up[jj], lap[jj]) - c_lds[jj] - ri);
    }
    #pragma unroll
    for (int m = 32; m >= 1; m >>= 1) acc += __shfl_xor(acc, m);
    if (l == 0) r[s * N_ + i] = ri + __logf(acc);
}

__global__ void __launch_bounds__(256)
matmul_out(const float* __restrict__ u, const float* __restrict__ la,
           const float* __restrict__ xT, const float* __restrict__ r,
           const float* __restrict__ c, float* __restrict__ out) {
    const int s = blockIdx.z, m0 = blockIdx.x * 64, b0 = blockIdx.y * 128;
    const int t = threadIdx.x, tx = t & 7, ty = t >> 3;
    __shared__ alignas(16) float Bs[16][64];
    float acc[4][8] = {};
    const float* up = u + (size_t)s * N_ * N_;
    const float* rp = r + s * N_;
    for (int k0 = 0; k0 < N_; k0 += 16) {
        __syncthreads();
        {
            const int kk = t >> 4, f4 = t & 15;
            const int k = k0 + kk;
            const float rk = rp[k];
            const float4 uv = *(const float4*)(up + (size_t)k * N_ + m0 + f4 * 4);
            const float4 lv = *(const float4*)(la + (size_t)k * N_ + m0 + f4 * 4);
            float4 p;
            p.x = __expf(la0_of(uv.x, lv.x) - rk);
            p.y = __expf(la0_of(uv.y, lv.y) - rk);
            p.z = __expf(la0_of(uv.z, lv.z) - rk);
            p.w = __expf(la0_of(uv.w, lv.w) - rk);
            *(float4*)(&Bs[kk][f4 * 4]) = p;
        }
        __syncthreads();
        #pragma unroll
        for (int kk = 0; kk < 16; ++kk) {
            const float4 a4 = *(const float4*)(xT + (size_t)(k0 + kk) * B_ + b0 + ty * 4);
            const float4 bA = *(const float4*)(&Bs[kk][tx * 8]);
            const float4 bB = *(const float4*)(&Bs[kk][tx * 8 + 4]);
            const float av[4] = {a4.x, a4.y, a4.z, a4.w};
            const float bv[8] = {bA.x, bA.y, bA.z, bA.w, bB.x, bB.y, bB.z, bB.w};
            #pragma unroll
            for (int rr = 0; rr < 4; ++rr)
                #pragma unroll
                for (int cc = 0; cc < 8; ++cc)
                    acc[rr][cc] += av[rr] * bv[cc];
        }
    }
    float cm[8];
    #pragma unroll
    for (int cc = 0; cc < 8; ++cc) cm[cc] = __expf(-c[s * N_ + m0 + tx * 8 + cc]);
    #pragma unroll
    for (int rr = 0; rr < 4; ++rr) {
        float4 o0, o1;
        o0.x = acc[rr][0] * cm[0]; o0.y = acc[rr][1] * cm[1];
        o0.z = acc[rr][2] * cm[2]; o0.w = acc[rr][3] * cm[3];
        o1.x = acc[rr][4] * cm[4]; o1.y = acc[rr][5] * cm[5];
        o1.z = acc[rr][6] * cm[6]; o1.w = acc[rr][7] * cm[7];
        float* op = out + ((size_t)s * B_ + b0 + ty * 4 + rr) * N_ + m0 + tx * 8;
        *(float4*)op       = o0;
        *(float4*)(op + 4) = o1;
    }
}

// ===========================================================================
extern "C" void kernel_launch(void* const* d_in, const int* in_sizes, int n_in,
                              void* d_out, int out_size, void* d_ws, size_t ws_size,
                              hipStream_t stream) {
    (void)in_sizes; (void)n_in; (void)out_size;
    const float* x  = (const float*)d_in[0];   // (256, 1024)
    const float* la = (const float*)d_in[1];   // (1024, 1024)
    const float* u  = (const float*)d_in[2];   // (16, 1024, 1024)
    float* out = (float*)d_out;                // (16, 256, 1024) f32

    const size_t KN = (size_t)S_ * N_ * N_;
    const size_t need = KN * 2 * 2               // Kb + KbT (bf16)
                      + (size_t)2 * S_ * N_ * 4; // U, V

    if (ws_size >= need) {
        unsigned short* Kb  = (unsigned short*)d_ws;
        unsigned short* KbT = Kb + KN;
        float* U = (float*)(KbT + KN);
        float* V = U + S_ * N_;

        build_K<<<2048, 256, 0, stream>>>(u, la, Kb);
        transpose_K<<<dim3(16, 16, 16), 256, 0, stream>>>(Kb, KbT);
        init_ones<<<S_ * N_ / 1024, 256, 0, stream>>>(U);

        for (int it = 0; it < ITERS; ++it) {
            pass_lin2<<<dim3(N_ / 8, S_), 256, 0, stream>>>(KbT, U, V);  // col norm
            pass_lin2<<<dim3(N_ / 8, S_), 256, 0, stream>>>(Kb,  V, U);  // row norm
        }
        mfma_out<<<dim3(N_ / 64, B_ / 128, S_), 256, 0, stream>>>(x, KbT, U, V, out);
    } else {
        float* r  = (float*)d_ws;
        float* c  = r + S_ * N_;
        float* xT = c + S_ * N_;
        hipMemsetAsync(d_ws, 0, 2 * S_ * N_ * sizeof(float), stream);
        transpose_x<<<dim3(N_ / 32, B_ / 32), dim3(32, 8), 0, stream>>>(x, xT);
        for (int it = 0; it < ITERS; ++it) {
            col_pass<<<dim3(N_ / 16, S_), 256, 0, stream>>>(u, la, r, c);
            row_pass<<<dim3(N_ / 4, S_),  256, 0, stream>>>(u, la, c, r);
        }
        matmul_out<<<dim3(N_ / 64, B_ / 128, S_), 256, 0, stream>>>(u, la, xT, r, c, out);
    }
}

// Round 5
// 272.222 us; speedup vs baseline: 4.5988x; 1.3374x over previous
//
#include <hip/hip_runtime.h>
#include <math.h>

// Problem constants (fixed by the reference: B=256, N=1024, S=16, 21 iters)
static constexpr int S_ = 16;
static constexpr int N_ = 1024;
static constexpr int B_ = 256;
static constexpr int ITERS = 21;
#define EPSC 1e-10f

using short8 = __attribute__((ext_vector_type(8))) short;
using f32x4  = __attribute__((ext_vector_type(4))) float;

// ---------------- bf16 helpers (raw ushort bits) ----------------
__device__ __forceinline__ float bf2f(unsigned short h) {
    union { unsigned int u; float f; } v; v.u = ((unsigned int)h) << 16; return v.f;
}
__device__ __forceinline__ unsigned short f2bf(float f) {
    union { float f; unsigned int u; } v; v.f = f;
    unsigned int r = v.u + 0x7fffu + ((v.u >> 16) & 1u);   // round-nearest-even
    return (unsigned short)(r >> 16);
}
__device__ __forceinline__ unsigned int pack2(float a, float b) {
    return (unsigned int)f2bf(a) | ((unsigned int)f2bf(b) << 16);
}

// la0 = log_alpha + gumbel_noise(u), noise = -log(EPS - log(u + EPS)).
__device__ __forceinline__ float la0_of(float uv, float lav) {
    float t1 = __logf(uv + EPSC);
    float t2 = EPSC - t1;
    return lav - __logf(t2);
}

// Block mapping shared by build_K2 / sink_iter: 1024 blocks.
// xcd = bid&7 (HW round-robin), sample s = xcd + 8*((bid>>3)&1)  -> each XCD
// owns 2 samples (2x2MB = 4MB = its L2), slab = bid>>4 (0..63, 16 rows each).
#define MAP_S_SLAB(bid, s, slab) \
    const int s = ((bid) & 7) + 8 * (((bid) >> 3) & 1); \
    const int slab = (bid) >> 4;

// ===========================================================================
// build_K2: K[s][i][j] = exp(la)/(EPS - log(u+EPS)) in bf16 (write Kb), and
// seed the col-pass partials with U=1:  partial[s][slab][j] = sum_i K[i][j].
// (colsum uses the ROUNDED bf16 K so all iterations see consistent values.)
// ===========================================================================
__global__ void __launch_bounds__(256)
build_K2(const float* __restrict__ u, const float* __restrict__ la,
         unsigned short* __restrict__ Kb, float* __restrict__ partial) {
    MAP_S_SLAB(blockIdx.x, s, slab)
    const int t = threadIdx.x, wv = t >> 6, l = t & 63;
    float cs[16];
    #pragma unroll
    for (int e = 0; e < 16; ++e) cs[e] = 0.f;

    const int i0 = slab * 16 + wv * 4;
    #pragma unroll
    for (int rr = 0; rr < 4; ++rr) {
        const int i = i0 + rr;
        const float* up  = u  + ((size_t)s * N_ + i) * N_;
        const float* lap = la + (size_t)i * N_;
        float kf[16];
        #pragma unroll
        for (int h = 0; h < 2; ++h) {        // column halves: 8l, 512+8l
            const int c = h * 512 + 8 * l;
            float4 ua = *(const float4*)(up + c);
            float4 ub = *(const float4*)(up + c + 4);
            float4 la4 = *(const float4*)(lap + c);
            float4 lb4 = *(const float4*)(lap + c + 4);
            const float uf[8] = {ua.x, ua.y, ua.z, ua.w, ub.x, ub.y, ub.z, ub.w};
            const float lf[8] = {la4.x, la4.y, la4.z, la4.w, lb4.x, lb4.y, lb4.z, lb4.w};
            unsigned int pk[4];
            #pragma unroll
            for (int e = 0; e < 4; ++e) {
                float k0 = __expf(lf[2*e])   / (EPSC - __logf(uf[2*e]   + EPSC));
                float k1 = __expf(lf[2*e+1]) / (EPSC - __logf(uf[2*e+1] + EPSC));
                unsigned short b0 = f2bf(k0), b1 = f2bf(k1);
                pk[e] = (unsigned int)b0 | ((unsigned int)b1 << 16);
                kf[h*8 + 2*e]     = bf2f(b0);
                kf[h*8 + 2*e + 1] = bf2f(b1);
            }
            *(uint4*)(Kb + ((size_t)s * N_ + i) * N_ + c) =
                make_uint4(pk[0], pk[1], pk[2], pk[3]);
        }
        #pragma unroll
        for (int e = 0; e < 16; ++e) cs[e] += kf[e];
    }

    // combine 4 waves' partial colsums, write partial[s][slab][:]
    __shared__ float lds[4][1024];
    *(float4*)&lds[wv][8*l]       = make_float4(cs[0], cs[1], cs[2], cs[3]);
    *(float4*)&lds[wv][8*l + 4]   = make_float4(cs[4], cs[5], cs[6], cs[7]);
    *(float4*)&lds[wv][512 + 8*l]     = make_float4(cs[8], cs[9], cs[10], cs[11]);
    *(float4*)&lds[wv][512 + 8*l + 4] = make_float4(cs[12], cs[13], cs[14], cs[15]);
    __syncthreads();
    const int j = t * 4;
    float4 p0 = *(const float4*)&lds[0][j];
    float4 p1 = *(const float4*)&lds[1][j];
    float4 p2 = *(const float4*)&lds[2][j];
    float4 p3 = *(const float4*)&lds[3][j];
    float4 o;
    o.x = p0.x + p1.x + p2.x + p3.x;  o.y = p0.y + p1.y + p2.y + p3.y;
    o.z = p0.z + p1.z + p2.z + p3.z;  o.w = p0.w + p1.w + p2.w + p3.w;
    *(float4*)(partial + ((size_t)s * 64 + slab) * N_ + j) = o;
}

// ===========================================================================
// reduce_V: V[s][j] = 1 / sum_slab partial[s][slab][j]. Deterministic order.
// Grid: 64 blocks x 256 threads.
// ===========================================================================
__global__ void __launch_bounds__(256)
reduce_V(const float* __restrict__ partial, float* __restrict__ V) {
    const int s = blockIdx.x >> 2;
    const int j = (blockIdx.x & 3) * 256 + threadIdx.x;
    const float* p = partial + (size_t)s * 64 * N_ + j;
    float acc = 0.f;
    #pragma unroll
    for (int q = 0; q < 64; ++q) acc += p[(size_t)q * N_];
    V[s * N_ + j] = 1.0f / acc;
}

// ===========================================================================
// sink_iter: fused row pass + next col-pass partials, ONE read of Kb/iter.
//   U_i = 1 / sum_j K[i][j] V_j ;  partial[s][slab][j] = sum_i K[i][j] U_i
// 1024 blocks (XCD-pinned samples), 16 rows/block, 4 rows/wave.
// ===========================================================================
__global__ void __launch_bounds__(256)
sink_iter(const unsigned short* __restrict__ Kb, const float* __restrict__ V,
          float* __restrict__ U, float* __restrict__ partial) {
    MAP_S_SLAB(blockIdx.x, s, slab)
    const int t = threadIdx.x, wv = t >> 6, l = t & 63;

    // lane-owned columns: 8l..8l+7 and 512+8l..512+8l+7
    float v[16];
    const float* Vp = V + s * N_;
    *(float4*)&v[0]  = *(const float4*)(Vp + 8*l);
    *(float4*)&v[4]  = *(const float4*)(Vp + 8*l + 4);
    *(float4*)&v[8]  = *(const float4*)(Vp + 512 + 8*l);
    *(float4*)&v[12] = *(const float4*)(Vp + 512 + 8*l + 4);

    float cs[16];
    #pragma unroll
    for (int e = 0; e < 16; ++e) cs[e] = 0.f;

    const int i0 = slab * 16 + wv * 4;
    const unsigned short* rowp = Kb + ((size_t)s * N_ + i0) * N_;
    #pragma unroll
    for (int rr = 0; rr < 4; ++rr, rowp += N_) {
        uint4 ka = *(const uint4*)(rowp + 8*l);
        uint4 kb = *(const uint4*)(rowp + 512 + 8*l);
        float kf[16];
        kf[0]  = bf2f((unsigned short)(ka.x & 0xffffu)); kf[1]  = bf2f((unsigned short)(ka.x >> 16));
        kf[2]  = bf2f((unsigned short)(ka.y & 0xffffu)); kf[3]  = bf2f((unsigned short)(ka.y >> 16));
        kf[4]  = bf2f((unsigned short)(ka.z & 0xffffu)); kf[5]  = bf2f((unsigned short)(ka.z >> 16));
        kf[6]  = bf2f((unsigned short)(ka.w & 0xffffu)); kf[7]  = bf2f((unsigned short)(ka.w >> 16));
        kf[8]  = bf2f((unsigned short)(kb.x & 0xffffu)); kf[9]  = bf2f((unsigned short)(kb.x >> 16));
        kf[10] = bf2f((unsigned short)(kb.y & 0xffffu)); kf[11] = bf2f((unsigned short)(kb.y >> 16));
        kf[12] = bf2f((unsigned short)(kb.z & 0xffffu)); kf[13] = bf2f((unsigned short)(kb.z >> 16));
        kf[14] = bf2f((unsigned short)(kb.w & 0xffffu)); kf[15] = bf2f((unsigned short)(kb.w >> 16));
        float dot = 0.f;
        #pragma unroll
        for (int e = 0; e < 16; ++e) dot += kf[e] * v[e];
        #pragma unroll
        for (int m = 32; m >= 1; m >>= 1) dot += __shfl_xor(dot, m);
        const float ui = 1.0f / dot;
        if (l == 0) U[s * N_ + i0 + rr] = ui;
        #pragma unroll
        for (int e = 0; e < 16; ++e) cs[e] += kf[e] * ui;
    }

    __shared__ float lds[4][1024];
    *(float4*)&lds[wv][8*l]       = make_float4(cs[0], cs[1], cs[2], cs[3]);
    *(float4*)&lds[wv][8*l + 4]   = make_float4(cs[4], cs[5], cs[6], cs[7]);
    *(float4*)&lds[wv][512 + 8*l]     = make_float4(cs[8], cs[9], cs[10], cs[11]);
    *(float4*)&lds[wv][512 + 8*l + 4] = make_float4(cs[12], cs[13], cs[14], cs[15]);
    __syncthreads();
    const int j = t * 4;
    float4 p0 = *(const float4*)&lds[0][j];
    float4 p1 = *(const float4*)&lds[1][j];
    float4 p2 = *(const float4*)&lds[2][j];
    float4 p3 = *(const float4*)&lds[3][j];
    float4 o;
    o.x = p0.x + p1.x + p2.x + p3.x;  o.y = p0.y + p1.y + p2.y + p3.y;
    o.z = p0.z + p1.z + p2.z + p3.z;  o.w = p0.w + p1.w + p2.w + p3.w;
    *(float4*)(partial + ((size_t)s * 64 + slab) * N_ + j) = o;
}

// ===========================================================================
// transpose_K: KbT[s][m][k] = Kb[s][k][m]  (runs AFTER the Sinkhorn loop;
// the partial buffer aliases the front of KbT and is dead by then).
// ===========================================================================
__global__ void __launch_bounds__(256)
transpose_K(const unsigned short* __restrict__ Kb, unsigned short* __restrict__ KbT) {
    const int s = blockIdx.z, k0 = blockIdx.x * 64, m0 = blockIdx.y * 64;
    __shared__ unsigned short tile[64][66];
    const int t = threadIdx.x, c4 = (t & 15) * 4, rr = t >> 4;
    const unsigned short* src = Kb + (size_t)s * N_ * N_;
    unsigned short* dst = KbT + (size_t)s * N_ * N_;
    #pragma unroll
    for (int q = 0; q < 4; ++q) {
        const int r = q * 16 + rr;
        ushort4 v = *(const ushort4*)(src + (size_t)(k0 + r) * N_ + m0 + c4);
        tile[r][c4] = v.x; tile[r][c4 + 1] = v.y; tile[r][c4 + 2] = v.z; tile[r][c4 + 3] = v.w;
    }
    __syncthreads();
    #pragma unroll
    for (int q = 0; q < 4; ++q) {
        const int rm = q * 16 + rr;
        ushort4 v;
        v.x = tile[c4][rm]; v.y = tile[c4 + 1][rm];
        v.z = tile[c4 + 2][rm]; v.w = tile[c4 + 3][rm];
        *(ushort4*)(dst + (size_t)(m0 + rm) * N_ + k0 + c4) = v;
    }
}

// ===========================================================================
// mfma_out: out[s][b][m] = V_m * sum_k (x[b][k]*U_k) * K[k][m], bf16 MFMA.
// Same validated layouts as round 4; adds register prefetch of the next
// K-tile so global latency hides under MFMA. BM=128, BN=64, BK=64.
// ===========================================================================
__global__ void __launch_bounds__(256)
mfma_out(const float* __restrict__ x, const unsigned short* __restrict__ KbT,
         const float* __restrict__ U, const float* __restrict__ V,
         float* __restrict__ out) {
    const int s  = blockIdx.z;
    const int m0 = blockIdx.x * 64;
    const int b0 = blockIdx.y * 128;
    const int t  = threadIdx.x;
    const int wid = t >> 6, l = t & 63;
    const int wr = wid >> 1, wc = wid & 1;

    __shared__ alignas(16) unsigned short lsA[128 * 64];  // [b][k] swizzled
    __shared__ alignas(16) unsigned short lsB[64 * 64];   // [m][k] swizzled, U folded

    f32x4 acc[4][2];
    #pragma unroll
    for (int fi = 0; fi < 4; ++fi)
        #pragma unroll
        for (int fj = 0; fj < 2; ++fj)
            acc[fi][fj] = (f32x4){0.f, 0.f, 0.f, 0.f};

    const unsigned short* Bp = KbT + ((size_t)s * N_ + m0) * N_;
    const float* Up = U + s * N_;

    // prefetch registers
    float4 xa[4], xb[4];
    uint4  kv[2];
    float4 ua[2], ub[2];

    auto load_tile = [&](int k0) {
        #pragma unroll
        for (int i = 0; i < 4; ++i) {
            const int Lb  = i * 4096 + t * 16;
            const int row = Lb >> 7;
            const int kb  = Lb & 127;
            const float* xp = x + (size_t)(b0 + row) * N_ + k0 + (kb >> 1);
            xa[i] = *(const float4*)xp;
            xb[i] = *(const float4*)(xp + 4);
        }
        #pragma unroll
        for (int i = 0; i < 2; ++i) {
            const int Lb  = i * 4096 + t * 16;
            const int row = Lb >> 7;
            const int kb  = Lb & 127;
            kv[i] = *(const uint4*)((const char*)Bp + (size_t)row * 2048 + (k0 << 1) + kb);
            const int ke = k0 + (kb >> 1);
            ua[i] = *(const float4*)(Up + ke);
            ub[i] = *(const float4*)(Up + ke + 4);
        }
    };

    load_tile(0);
    for (int k0 = 0; k0 < N_; k0 += 64) {
        __syncthreads();
        // ---- write staged regs -> LDS (A: f32->bf16; B: K*U -> bf16) ----
        #pragma unroll
        for (int i = 0; i < 4; ++i) {
            const int Lb  = i * 4096 + t * 16;
            const int row = Lb >> 7;
            const int kb  = Lb & 127;
            uint4 pk = make_uint4(pack2(xa[i].x, xa[i].y), pack2(xa[i].z, xa[i].w),
                                  pack2(xb[i].x, xb[i].y), pack2(xb[i].z, xb[i].w));
            *(uint4*)((char*)lsA + (row << 7) + (kb ^ ((row & 7) << 4))) = pk;
        }
        #pragma unroll
        for (int i = 0; i < 2; ++i) {
            const int Lb  = i * 4096 + t * 16;
            const int row = Lb >> 7;
            const int kb  = Lb & 127;
            uint4 pk;
            pk.x = pack2(bf2f((unsigned short)(kv[i].x & 0xffffu)) * ua[i].x,
                         bf2f((unsigned short)(kv[i].x >> 16))     * ua[i].y);
            pk.y = pack2(bf2f((unsigned short)(kv[i].y & 0xffffu)) * ua[i].z,
                         bf2f((unsigned short)(kv[i].y >> 16))     * ua[i].w);
            pk.z = pack2(bf2f((unsigned short)(kv[i].z & 0xffffu)) * ub[i].x,
                         bf2f((unsigned short)(kv[i].z >> 16))     * ub[i].y);
            pk.w = pack2(bf2f((unsigned short)(kv[i].w & 0xffffu)) * ub[i].z,
                         bf2f((unsigned short)(kv[i].w >> 16))     * ub[i].w);
            *(uint4*)((char*)lsB + (row << 7) + (kb ^ ((row & 7) << 4))) = pk;
        }
        __syncthreads();
        if (k0 + 64 < N_) load_tile(k0 + 64);   // prefetch next tile
        // ---- MFMA: fragment k = ks*32 + (l>>4)*8 + e, row index = l&15 ----
        #pragma unroll
        for (int ks = 0; ks < 2; ++ks) {
            const int koff = ks * 64 + ((l >> 4) << 4);   // byte offset in row
            short8 afr[4], bfr[2];
            #pragma unroll
            for (int fi = 0; fi < 4; ++fi) {
                const int r = wr * 64 + fi * 16 + (l & 15);
                afr[fi] = *(const short8*)((const char*)lsA + (r << 7) + (koff ^ ((r & 7) << 4)));
            }
            #pragma unroll
            for (int fj = 0; fj < 2; ++fj) {
                const int r = wc * 32 + fj * 16 + (l & 15);
                bfr[fj] = *(const short8*)((const char*)lsB + (r << 7) + (koff ^ ((r & 7) << 4)));
            }
            #pragma unroll
            for (int fi = 0; fi < 4; ++fi)
                #pragma unroll
                for (int fj = 0; fj < 2; ++fj)
                    acc[fi][fj] = __builtin_amdgcn_mfma_f32_16x16x32_bf16(
                        afr[fi], bfr[fj], acc[fi][fj], 0, 0, 0);
        }
    }
    // ---- epilogue: D[i][j]: col j = l&15, row i = 4*(l>>4)+e; scale by V ----
    #pragma unroll
    for (int fj = 0; fj < 2; ++fj) {
        const int m = m0 + wc * 32 + fj * 16 + (l & 15);
        const float vm = V[s * N_ + m];
        #pragma unroll
        for (int fi = 0; fi < 4; ++fi) {
            const int b = b0 + wr * 64 + fi * 16 + ((l >> 4) << 2);
            float* op = out + ((size_t)s * B_ + b) * N_ + m;
            #pragma unroll
            for (int e = 0; e < 4; ++e)
                op[(size_t)e * N_] = acc[fi][fj][e] * vm;
        }
    }
}

// ===========================================================================
// FALLBACK PATH (round-1 proven kernels) — used only if ws is too small.
// ===========================================================================
__global__ void __launch_bounds__(256)
transpose_x(const float* __restrict__ x, float* __restrict__ xT) {
    __shared__ float tile[32][33];
    const int tx = threadIdx.x, ty = threadIdx.y;
    const int gx = blockIdx.x * 32, gy = blockIdx.y * 32;
    #pragma unroll
    for (int i = 0; i < 4; ++i)
        tile[ty + i * 8][tx] = x[(gy + ty + i * 8) * N_ + gx + tx];
    __syncthreads();
    #pragma unroll
    for (int i = 0; i < 4; ++i)
        xT[(size_t)(gx + ty + i * 8) * B_ + gy + tx] = tile[tx][ty + i * 8];
}

__global__ void __launch_bounds__(256)
col_pass(const float* __restrict__ u, const float* __restrict__ la,
         const float* __restrict__ r, float* __restrict__ c) {
    const int s = blockIdx.y, t = threadIdx.x;
    const int tx = t & 15, rg = t >> 4;
    const int j = blockIdx.x * 16 + tx;
    __shared__ alignas(16) float r_lds[N_];
    ((float4*)r_lds)[t] = ((const float4*)(r + s * N_))[t];
    __syncthreads();
    const float cj = c[s * N_ + j];
    const float* up = u + (size_t)s * N_ * N_;
    const int i0 = rg * 64;
    float acc = 0.f;
    #pragma unroll 4
    for (int ii = 0; ii < 64; ++ii) {
        const int i = i0 + ii;
        acc += __expf(la0_of(up[(size_t)i * N_ + j], la[i * N_ + j]) - r_lds[i] - cj);
    }
    __shared__ float sums[16][17];
    sums[rg][tx] = acc;
    __syncthreads();
    if (t < 16) {
        float tot = 0.f;
        #pragma unroll
        for (int k = 0; k < 16; ++k) tot += sums[k][t];
        c[s * N_ + blockIdx.x * 16 + t] = cj + __logf(tot);
    }
}

__global__ void __launch_bounds__(256)
row_pass(const float* __restrict__ u, const float* __restrict__ la,
         const float* __restrict__ c, float* __restrict__ r) {
    const int s = blockIdx.y, t = threadIdx.x;
    const int w = t >> 6, l = t & 63;
    const int i = blockIdx.x * 4 + w;
    __shared__ alignas(16) float c_lds[N_];
    ((float4*)c_lds)[t] = ((const float4*)(c + s * N_))[t];
    __syncthreads();
    const float ri = r[s * N_ + i];
    const float* up = u + (size_t)s * N_ * N_ + (size_t)i * N_;
    const float* lap = la + (size_t)i * N_;
    float acc = 0.f;
    #pragma unroll
    for (int k = 0; k < 16; ++k) {
        const int jj = l + (k << 6);
        acc += __expf(la0_of(up[jj], lap[jj]) - c_lds[jj] - ri);
    }
    #pragma unroll
    for (int m = 32; m >= 1; m >>= 1) acc += __shfl_xor(acc, m);
    if (l == 0) r[s * N_ + i] = ri + __logf(acc);
}

__global__ void __launch_bounds__(256)
matmul_out(const float* __restrict__ u, const float* __restrict__ la,
           const float* __restrict__ xT, const float* __restrict__ r,
           const float* __restrict__ c, float* __restrict__ out) {
    const int s = blockIdx.z, m0 = blockIdx.x * 64, b0 = blockIdx.y * 128;
    const int t = threadIdx.x, tx = t & 7, ty = t >> 3;
    __shared__ alignas(16) float Bs[16][64];
    float acc[4][8] = {};
    const float* up = u + (size_t)s * N_ * N_;
    const float* rp = r + s * N_;
    for (int k0 = 0; k0 < N_; k0 += 16) {
        __syncthreads();
        {
            const int kk = t >> 4, f4 = t & 15;
            const int k = k0 + kk;
            const float rk = rp[k];
            const float4 uv = *(const float4*)(up + (size_t)k * N_ + m0 + f4 * 4);
            const float4 lv = *(const float4*)(la + (size_t)k * N_ + m0 + f4 * 4);
            float4 p;
            p.x = __expf(la0_of(uv.x, lv.x) - rk);
            p.y = __expf(la0_of(uv.y, lv.y) - rk);
            p.z = __expf(la0_of(uv.z, lv.z) - rk);
            p.w = __expf(la0_of(uv.w, lv.w) - rk);
            *(float4*)(&Bs[kk][f4 * 4]) = p;
        }
        __syncthreads();
        #pragma unroll
        for (int kk = 0; kk < 16; ++kk) {
            const float4 a4 = *(const float4*)(xT + (size_t)(k0 + kk) * B_ + b0 + ty * 4);
            const float4 bA = *(const float4*)(&Bs[kk][tx * 8]);
            const float4 bB = *(const float4*)(&Bs[kk][tx * 8 + 4]);
            const float av[4] = {a4.x, a4.y, a4.z, a4.w};
            const float bv[8] = {bA.x, bA.y, bA.z, bA.w, bB.x, bB.y, bB.z, bB.w};
            #pragma unroll
            for (int rr = 0; rr < 4; ++rr)
                #pragma unroll
                for (int cc = 0; cc < 8; ++cc)
                    acc[rr][cc] += av[rr] * bv[cc];
        }
    }
    float cm[8];
    #pragma unroll
    for (int cc = 0; cc < 8; ++cc) cm[cc] = __expf(-c[s * N_ + m0 + tx * 8 + cc]);
    #pragma unroll
    for (int rr = 0; rr < 4; ++rr) {
        float4 o0, o1;
        o0.x = acc[rr][0] * cm[0]; o0.y = acc[rr][1] * cm[1];
        o0.z = acc[rr][2] * cm[2]; o0.w = acc[rr][3] * cm[3];
        o1.x = acc[rr][4] * cm[4]; o1.y = acc[rr][5] * cm[5];
        o1.z = acc[rr][6] * cm[6]; o1.w = acc[rr][7] * cm[7];
        float* op = out + ((size_t)s * B_ + b0 + ty * 4 + rr) * N_ + m0 + tx * 8;
        *(float4*)op       = o0;
        *(float4*)(op + 4) = o1;
    }
}

// ===========================================================================
extern "C" void kernel_launch(void* const* d_in, const int* in_sizes, int n_in,
                              void* d_out, int out_size, void* d_ws, size_t ws_size,
                              hipStream_t stream) {
    (void)in_sizes; (void)n_in; (void)out_size;
    const float* x  = (const float*)d_in[0];   // (256, 1024)
    const float* la = (const float*)d_in[1];   // (1024, 1024)
    const float* u  = (const float*)d_in[2];   // (16, 1024, 1024)
    float* out = (float*)d_out;                // (16, 256, 1024) f32

    const size_t KN = (size_t)S_ * N_ * N_;
    const size_t need = KN * 2 * 2               // Kb + KbT (bf16)
                      + (size_t)2 * S_ * N_ * 4; // U, V  (== round-2 layout)

    if (ws_size >= need) {
        unsigned short* Kb  = (unsigned short*)d_ws;
        unsigned short* KbT = Kb + KN;
        float* partial = (float*)KbT;            // 4 MB, aliases KbT (dead
                                                 // before transpose_K runs)
        float* U = (float*)(KbT + KN);
        float* V = U + S_ * N_;

        // 1) build K (bf16) + seed col-pass partials with U=1
        build_K2<<<1024, 256, 0, stream>>>(u, la, Kb, partial);

        // 2) 21 Sinkhorn iterations: finalize V, then fused row+colsum pass
        for (int it = 0; it < ITERS; ++it) {
            reduce_V<<<64, 256, 0, stream>>>(partial, V);
            sink_iter<<<1024, 256, 0, stream>>>(Kb, V, U, partial);
        }

        // 3) KbT for the matmul's B operand (partial is dead now)
        transpose_K<<<dim3(16, 16, 16), 256, 0, stream>>>(Kb, KbT);

        // 4) out = diag-scaled GEMM via bf16 MFMA
        mfma_out<<<dim3(N_ / 64, B_ / 128, S_), 256, 0, stream>>>(x, KbT, U, V, out);
    } else {
        float* r  = (float*)d_ws;
        float* c  = r + S_ * N_;
        float* xT = c + S_ * N_;
        hipMemsetAsync(d_ws, 0, 2 * S_ * N_ * sizeof(float), stream);
        transpose_x<<<dim3(N_ / 32, B_ / 32), dim3(32, 8), 0, stream>>>(x, xT);
        for (int it = 0; it < ITERS; ++it) {
            col_pass<<<dim3(N_ / 16, S_), 256, 0, stream>>>(u, la, r, c);
            row_pass<<<dim3(N_ / 4, S_),  256, 0, stream>>>(u, la, c, r);
        }
        matmul_out<<<dim3(N_ / 64, B_ / 128, S_), 256, 0, stream>>>(u, la, xT, r, c, out);
    }
}